// Round 1
// baseline (192.186 us; speedup 1.0000x reference)
//
#include <hip/hip_runtime.h>

#define BATCH 16
#define NQ    2048
#define NK    2048
#define DD    128
#define DVV   128

typedef __bf16 bf16_t;
typedef __bf16 bf16x2 __attribute__((ext_vector_type(2)));
typedef __bf16 bf16x4 __attribute__((ext_vector_type(4)));
typedef __bf16 bf16x8 __attribute__((ext_vector_type(8)));
typedef float  f32x4  __attribute__((ext_vector_type(4)));

// LDS row strides (bf16 elements) chosen for 16B alignment + <=2-way bank conflicts
#define KSTR 152   // 304B rows: 76 words ≡ 12 mod 32 -> 2-way
#define VSTR 88    // 176B rows: 44 words ≡ 12 mod 32 -> 2-way
#define PSTR 72    // 144B rows: 36 words ≡  4 mod 32 -> 2-way

__device__ __forceinline__ int load_valid_len(const int* VL, int b) {
  // valid_lens is int64 in the reference; JAX x64-off typically gives int32.
  // Detect int64 little-endian layout: odd words all zero, even words in range.
  bool looks64 = true;
#pragma unroll
  for (int i = 0; i < 16; ++i) {
    int hi = VL[2 * i + 1];
    unsigned lo = (unsigned)VL[2 * i];
    looks64 = looks64 && (hi == 0) && (lo <= 2048u);
  }
  int L = looks64 ? VL[2 * b] : VL[b];
  return min(max(L, 0), NK);
}

// ws[b][dv] = sum_{k >= L_b} V[b][k][dv]   (fp32, via atomicAdd partials)
__global__ void suffix_kernel(const float* __restrict__ V, const int* __restrict__ VL,
                              float* __restrict__ ws) {
  int b = blockIdx.x;
  int kc = blockIdx.y;
  int L = load_valid_len(VL, b);
  int k0 = kc * 128, k1 = k0 + 128;
  int lo = max(L, k0);
  int t = threadIdx.x;
  int dv = t & 127;
  int h = t >> 7;
  float s = 0.f;
  for (int k = lo + h; k < k1; k += 2)
    s += V[((size_t)b * NK + k) * DVV + dv];
  __shared__ float part[128];
  if (h == 0) part[dv] = s;
  __syncthreads();
  if (h == 1) atomicAdd(&ws[b * DVV + dv], part[dv] + s);
}

__device__ __forceinline__ f32x4 mfma16(bf16x8 a, bf16x8 b, f32x4 c) {
  return __builtin_amdgcn_mfma_f32_16x16x32_bf16(a, b, c, 0, 0, 0);
}

__launch_bounds__(256, 2)
__global__ void attn_kernel(const float* __restrict__ Q, const float* __restrict__ K,
                            const float* __restrict__ V, const int* __restrict__ VL,
                            const float* __restrict__ sufV, float* __restrict__ Out) {
  const int flat = blockIdx.x;
  const int b  = flat & 15;       // interleave batches across blocks for load balance
  const int qt = flat >> 4;       // 0..31
  const int L  = load_valid_len(VL, b);

  __shared__ bf16_t sK[64 * KSTR];    // K tile  [key][dim]
  __shared__ bf16_t sVT[128 * VSTR];  // V tile transposed [dv][key]
  __shared__ bf16_t sP[4 * 16 * PSTR];// per-wave P scratch [row][key]

  const int tid  = threadIdx.x;
  const int wave = tid >> 6;
  const int lane = tid & 63;
  const int col  = lane & 15;
  const int quad = lane >> 4;

  const float* Qb = Q + ((size_t)b * NQ + qt * 64 + wave * 16) * DD;
  const float* Kb = K + (size_t)b * NK * DD;
  const float* Vb = V + (size_t)b * NK * DVV;

  // ---- Q fragments in registers, pre-scaled by 1/sqrt(128), A-layout:
  // A[m=lane&15][k = ks*32 + quad*8 + j]
  bf16x8 qf[4];
  {
    const float sc = 0.08838834764831845f;
    const float* qrow = Qb + (size_t)col * DD + quad * 8;
#pragma unroll
    for (int ks = 0; ks < 4; ++ks) {
      float4 u0 = *(const float4*)(qrow + ks * 32);
      float4 u1 = *(const float4*)(qrow + ks * 32 + 4);
      bf16x8 f;
      f[0] = (bf16_t)(u0.x * sc); f[1] = (bf16_t)(u0.y * sc);
      f[2] = (bf16_t)(u0.z * sc); f[3] = (bf16_t)(u0.w * sc);
      f[4] = (bf16_t)(u1.x * sc); f[5] = (bf16_t)(u1.y * sc);
      f[6] = (bf16_t)(u1.z * sc); f[7] = (bf16_t)(u1.w * sc);
      qf[ks] = f;
    }
  }

  f32x4 Oacc[8];
#pragma unroll
  for (int o = 0; o < 8; ++o) Oacc[o] = (f32x4){0.f, 0.f, 0.f, 0.f};
  float m_i[4], l_i[4];
#pragma unroll
  for (int r = 0; r < 4; ++r) { m_i[r] = -1e30f; l_i[r] = 0.f; }

  const int ktiles = (L + 63) >> 6;   // only tiles containing valid keys
  for (int kt = 0; kt < ktiles; ++kt) {
    // ---- stage K tile: [64][128] fp32 -> bf16 LDS, row-major (coalesced reads)
    {
      int r0 = tid >> 5;
      int d4 = (tid & 31) * 4;
      const float* src = Kb + ((size_t)(kt * 64) + r0) * DD + d4;
#pragma unroll
      for (int i = 0; i < 8; ++i) {
        float4 u = *(const float4*)(src + (size_t)i * 8 * DD);
        bf16x4 w4 = {(bf16_t)u.x, (bf16_t)u.y, (bf16_t)u.z, (bf16_t)u.w};
        *(bf16x4*)&sK[(r0 + i * 8) * KSTR + d4] = w4;
      }
    }
    // ---- stage V tile transposed: key-pair packed b32 writes (conflict-free)
    {
      int r2 = (tid & 31) * 2;
      int dbase = (tid >> 5) * 4;
#pragma unroll
      for (int i = 0; i < 4; ++i) {
        int d4 = dbase + i * 32;
        const float* s0 = Vb + ((size_t)(kt * 64) + r2) * DVV + d4;
        float4 u0 = *(const float4*)s0;
        float4 u1 = *(const float4*)(s0 + DVV);
        *(bf16x2*)&sVT[(d4 + 0) * VSTR + r2] = (bf16x2){(bf16_t)u0.x, (bf16_t)u1.x};
        *(bf16x2*)&sVT[(d4 + 1) * VSTR + r2] = (bf16x2){(bf16_t)u0.y, (bf16_t)u1.y};
        *(bf16x2*)&sVT[(d4 + 2) * VSTR + r2] = (bf16x2){(bf16_t)u0.z, (bf16_t)u1.z};
        *(bf16x2*)&sVT[(d4 + 3) * VSTR + r2] = (bf16x2){(bf16_t)u0.w, (bf16_t)u1.w};
      }
    }
    __syncthreads();

    // ---- S = Q * K^T  (16 q-rows x 64 keys per wave)
    f32x4 s[4];
#pragma unroll
    for (int nt = 0; nt < 4; ++nt) s[nt] = (f32x4){0.f, 0.f, 0.f, 0.f};
#pragma unroll
    for (int ks = 0; ks < 4; ++ks) {
      bf16x8 a = qf[ks];
#pragma unroll
      for (int nt = 0; nt < 4; ++nt) {
        bf16x8 bb = *(const bf16x8*)&sK[(nt * 16 + col) * KSTR + ks * 32 + quad * 8];
        s[nt] = mfma16(a, bb, s[nt]);
      }
    }

    // ---- mask (exclude k >= L; handled by constant-suffix merge) + online softmax
    const int key0 = kt * 64;
    float sv[4][4];
    float mloc[4] = {-1e30f, -1e30f, -1e30f, -1e30f};
#pragma unroll
    for (int nt = 0; nt < 4; ++nt) {
      int key = key0 + nt * 16 + col;
      bool valid = key < L;
#pragma unroll
      for (int r = 0; r < 4; ++r) {
        float v = valid ? s[nt][r] : -1e30f;   // Q pre-scaled, s already scaled
        sv[nt][r] = v;
        mloc[r] = fmaxf(mloc[r], v);
      }
    }
#pragma unroll
    for (int off = 1; off < 16; off <<= 1) {
#pragma unroll
      for (int r = 0; r < 4; ++r)
        mloc[r] = fmaxf(mloc[r], __shfl_xor(mloc[r], off, 64));
    }
    float al[4];
#pragma unroll
    for (int r = 0; r < 4; ++r) {
      float mn = fmaxf(m_i[r], mloc[r]);
      al[r] = __expf(m_i[r] - mn);
      m_i[r] = mn;
    }
    float lloc[4] = {0.f, 0.f, 0.f, 0.f};
#pragma unroll
    for (int nt = 0; nt < 4; ++nt)
#pragma unroll
      for (int r = 0; r < 4; ++r) {
        float p = __expf(sv[nt][r] - m_i[r]);
        sv[nt][r] = p;
        lloc[r] += p;
      }
#pragma unroll
    for (int off = 1; off < 16; off <<= 1) {
#pragma unroll
      for (int r = 0; r < 4; ++r)
        lloc[r] += __shfl_xor(lloc[r], off, 64);
    }
#pragma unroll
    for (int r = 0; r < 4; ++r) l_i[r] = l_i[r] * al[r] + lloc[r];
#pragma unroll
    for (int o = 0; o < 8; ++o)
#pragma unroll
      for (int r = 0; r < 4; ++r) Oacc[o][r] *= al[r];

    // ---- P: C-layout -> A-layout via per-wave LDS (same-wave DS ordering)
    bf16_t* pw = &sP[wave * 16 * PSTR];
#pragma unroll
    for (int nt = 0; nt < 4; ++nt)
#pragma unroll
      for (int r = 0; r < 4; ++r)
        pw[(quad * 4 + r) * PSTR + nt * 16 + col] = (bf16_t)sv[nt][r];

    // ---- O += P * V
#pragma unroll
    for (int ks2 = 0; ks2 < 2; ++ks2) {
      bf16x8 a = *(const bf16x8*)&pw[(lane & 15) * PSTR + ks2 * 32 + quad * 8];
#pragma unroll
      for (int o = 0; o < 8; ++o) {
        bf16x8 bb = *(const bf16x8*)&sVT[(o * 16 + col) * VSTR + ks2 * 32 + quad * 8];
        Oacc[o] = mfma16(a, bb, Oacc[o]);
      }
    }
    __syncthreads();
  }

  // ---- merge the constant-score (1e-8) masked suffix analytically
  if (L < NK) {
    const float c = 1e-8f;
    const float w = (float)(NK - L);
    float a2[4], ec[4];
#pragma unroll
    for (int r = 0; r < 4; ++r) {
      float mn = fmaxf(m_i[r], c);
      a2[r] = __expf(m_i[r] - mn);
      ec[r] = __expf(c - mn);
      l_i[r] = l_i[r] * a2[r] + w * ec[r];
    }
    const float* sfv = sufV + b * DVV;
#pragma unroll
    for (int o = 0; o < 8; ++o) {
      float svv = sfv[o * 16 + col];
#pragma unroll
      for (int r = 0; r < 4; ++r) Oacc[o][r] = Oacc[o][r] * a2[r] + ec[r] * svv;
    }
  }

  float invl[4];
#pragma unroll
  for (int r = 0; r < 4; ++r) invl[r] = 1.0f / l_i[r];

  float* Ob = Out + ((size_t)b * NQ + qt * 64 + wave * 16) * DVV;
#pragma unroll
  for (int o = 0; o < 8; ++o)
#pragma unroll
    for (int r = 0; r < 4; ++r)
      Ob[(size_t)(quad * 4 + r) * DVV + o * 16 + col] = Oacc[o][r] * invl[r];
}

extern "C" void kernel_launch(void* const* d_in, const int* in_sizes, int n_in,
                              void* d_out, int out_size, void* d_ws, size_t ws_size,
                              hipStream_t stream) {
  const float* Q  = (const float*)d_in[0];
  const float* K  = (const float*)d_in[1];
  const float* V  = (const float*)d_in[2];
  const int*   VL = (const int*)d_in[3];
  float* out = (float*)d_out;
  float* ws  = (float*)d_ws;

  hipMemsetAsync(ws, 0, BATCH * DVV * sizeof(float), stream);
  dim3 g1(BATCH, 16);
  suffix_kernel<<<g1, 256, 0, stream>>>(V, VL, ws);
  attn_kernel<<<BATCH * (NQ / 64), 256, 0, stream>>>(Q, K, V, VL, ws, out);
}

// Round 3
// 179.271 us; speedup vs baseline: 1.0720x; 1.0720x over previous
//
#include <hip/hip_runtime.h>
#include <stdint.h>

#define BATCH 16
#define NQ    2048
#define NK    2048
#define DD    128
#define DVV   128

typedef __bf16 bf16_t;
typedef __bf16 bf16x2 __attribute__((ext_vector_type(2)));
typedef __bf16 bf16x4 __attribute__((ext_vector_type(4)));
typedef __bf16 bf16x8 __attribute__((ext_vector_type(8)));
typedef float  f32x4  __attribute__((ext_vector_type(4)));

// ---------------- ws layout (bytes) ----------------
#define QB_OFF  ((size_t)0)                       // bf16 Q, scaled by log2e/sqrt(128): 8 MB
#define KB_OFF  ((size_t)8 * 1024 * 1024)         // bf16 K: 8 MB
#define VT_OFF  ((size_t)16 * 1024 * 1024)        // bf16 V^T [b][dv][k]: 8 MB
#define SUF_OFF ((size_t)24 * 1024 * 1024)        // fp32 sufV[b][dv]: 8 KB
#define OP_OFF  (SUF_OFF + 65536)                 // fp32 O partials: 1024 * 8192 * 4 = 32 MB
#define LP_OFF  (OP_OFF + (size_t)1024 * 8192 * 4)// fp32 l partials: 1024 * 64 * 4
#define WS_NEED (LP_OFF + (size_t)1024 * 64 * 4)

__device__ __forceinline__ int load_valid_len(const int* VL, int b) {
  bool looks64 = true;
#pragma unroll
  for (int i = 0; i < 16; ++i) {
    int hi = VL[2 * i + 1];
    unsigned lo = (unsigned)VL[2 * i];
    looks64 = looks64 && (hi == 0) && (lo <= 2048u);
  }
  int L = looks64 ? VL[2 * b] : VL[b];
  return min(max(L, 0), NK);
}

__device__ __forceinline__ void gld16(const void* g, void* l) {
  __builtin_amdgcn_global_load_lds(
      (const __attribute__((address_space(1))) unsigned int*)g,
      (__attribute__((address_space(3))) unsigned int*)l, 16, 0, 0);
}

__device__ __forceinline__ f32x4 mfma16(bf16x8 a, bf16x8 b, f32x4 c) {
  return __builtin_amdgcn_mfma_f32_16x16x32_bf16(a, b, c, 0, 0, 0);
}

// ---------------- preprocessing ----------------

// Q,K fp32 -> bf16 (Q scaled by log2e/sqrt(128))
__global__ void convqk_kernel(const float* __restrict__ Q, const float* __restrict__ K,
                              bf16_t* __restrict__ Qb, bf16_t* __restrict__ Kb) {
  const float sc = 0.1275174307f;  // log2(e)/sqrt(128)
  size_t gt = (size_t)blockIdx.x * 256 + threadIdx.x;
  size_t base = gt * 32;
  const size_t NQK = (size_t)BATCH * NQ * DD;  // 4194304
  bool isQ = base < NQK;
  const float* src = isQ ? (Q + base) : (K + (base - NQK));
  bf16_t* dst = isQ ? (Qb + base) : (Kb + (base - NQK));
  float s = isQ ? sc : 1.0f;
#pragma unroll
  for (int i = 0; i < 4; ++i) {
    float4 a = ((const float4*)src)[i * 2];
    float4 b = ((const float4*)src)[i * 2 + 1];
    bf16x8 o;
    o[0] = (bf16_t)(a.x * s); o[1] = (bf16_t)(a.y * s);
    o[2] = (bf16_t)(a.z * s); o[3] = (bf16_t)(a.w * s);
    o[4] = (bf16_t)(b.x * s); o[5] = (bf16_t)(b.y * s);
    o[6] = (bf16_t)(b.z * s); o[7] = (bf16_t)(b.w * s);
    ((bf16x8*)dst)[i] = o;
  }
}

// V fp32 [b][k][dv] -> bf16 V^T [b][dv][k]; also suffix sums sufV[b][dv] = sum_{k>=L} V
__global__ void vtrans_kernel(const float* __restrict__ V, const int* __restrict__ VL,
                              bf16_t* __restrict__ Vt, float* __restrict__ sufV) {
  __shared__ bf16_t tile[128 * 72];  // [dv][key], stride 72 (144B rows, 16B-aligned)
  __shared__ float suf[128];
  int b = blockIdx.x & 15, kt = blockIdx.x >> 4;
  int L = load_valid_len(VL, b);
  int t = threadIdx.x;
  if (t < 128) suf[t] = 0.f;
  __syncthreads();
  int r = t >> 2;          // key row 0..63
  int c0 = (t & 3) * 32;   // dv base
  int k = kt * 64 + r;
  const float* src = V + ((size_t)b * NK + k) * DVV + c0;
  bool acc = (k >= L);
#pragma unroll
  for (int j = 0; j < 32; j += 4) {
    float4 u = *(const float4*)(src + j);
    tile[(c0 + j + 0) * 72 + r] = (bf16_t)u.x;
    tile[(c0 + j + 1) * 72 + r] = (bf16_t)u.y;
    tile[(c0 + j + 2) * 72 + r] = (bf16_t)u.z;
    tile[(c0 + j + 3) * 72 + r] = (bf16_t)u.w;
    if (acc) {
      atomicAdd(&suf[c0 + j + 0], u.x);
      atomicAdd(&suf[c0 + j + 1], u.y);
      atomicAdd(&suf[c0 + j + 2], u.z);
      atomicAdd(&suf[c0 + j + 3], u.w);
    }
  }
  __syncthreads();
  int dv = t >> 1, half = t & 1;
  bf16_t* dst = Vt + (size_t)b * DVV * NK + (size_t)dv * NK + kt * 64 + half * 32;
  const bf16_t* srow = &tile[dv * 72 + half * 32];
#pragma unroll
  for (int j = 0; j < 4; ++j)
    ((bf16x8*)dst)[j] = ((const bf16x8*)srow)[j];
  if (t < 128) atomicAdd(&sufV[b * DVV + t], suf[t]);
}

// ---------------- main attention (split-K, fixed softmax ref m=0, log2 domain) ----------------
// LDS: sK 64x128 bf16 (16KB, XOR-swizzled chunks), sVt 128x64 bf16 (16KB, swizzled),
//      sP 4 waves x 16x64 bf16 (8KB, swizzled). Total exactly 40KB -> 4 blocks/CU.
__launch_bounds__(256, 4)
__global__ void attn_kernel(const bf16_t* __restrict__ Qb, const bf16_t* __restrict__ Kb,
                            const bf16_t* __restrict__ Vt, const int* __restrict__ VL,
                            float* __restrict__ Opart, float* __restrict__ lpart) {
  __shared__ bf16_t sK[64 * 128];
  __shared__ bf16_t sVt[128 * 64];
  __shared__ bf16_t sP[4 * 16 * 64];

  const int flat = blockIdx.x;
  const int s  = flat & 1;
  const int b  = (flat >> 1) & 15;
  const int qt = flat >> 5;
  const int L  = load_valid_len(VL, b);
  const int ktiles = (L + 63) >> 6;
  const int t0 = (s * ktiles) >> 1;
  const int t1 = ((s + 1) * ktiles) >> 1;

  const int tid = threadIdx.x;
  const int wave = tid >> 6;
  const int lane = tid & 63;
  const int col = lane & 15;
  const int quad = lane >> 4;

  // Q fragments (already bf16, scaled, log2 domain)
  bf16x8 qf[4];
  {
    const bf16_t* qrow = Qb + ((size_t)b * NQ + qt * 64 + wave * 16 + col) * DD + quad * 8;
#pragma unroll
    for (int ks = 0; ks < 4; ++ks) qf[ks] = *(const bf16x8*)(qrow + ks * 32);
  }

  // staging source offsets (bytes within batch), swizzle folded into GLOBAL address;
  // LDS dest is contiguous base + lane*16 (global_load_lds constraint).
  const char* Kbyte = (const char*)Kb + (size_t)b * NK * DD * 2;
  const char* Vbyte = (const char*)Vt + (size_t)b * DVV * NK * 2;
  int koff[4], voff[4];
#pragma unroll
  for (int i = 0; i < 4; ++i) {
    int krow = wave * 16 + i * 4 + (lane >> 4);
    koff[i] = krow * 256 + (((lane & 15) ^ (krow & 15)) * 16);
    int vrow = wave * 32 + i * 8 + (lane >> 3);
    voff[i] = vrow * (NK * 2) + (((lane & 7) ^ ((lane >> 3) & 7)) * 16);
  }
  bf16_t* kl = sK + wave * 2048;   // 4KB LDS per wave
  bf16_t* vl = sVt + wave * 2048;
  bf16_t* pw = sP + wave * 1024;   // 2KB per-wave P scratch

  f32x4 Oacc[8];
#pragma unroll
  for (int o = 0; o < 8; ++o) Oacc[o] = (f32x4){0.f, 0.f, 0.f, 0.f};
  float lsum[4] = {0.f, 0.f, 0.f, 0.f};

  for (int kt = t0; kt < t1; ++kt) {
    const char* kb = Kbyte + (size_t)kt * 16384;
    const char* vb = Vbyte + (size_t)kt * 128;
#pragma unroll
    for (int i = 0; i < 4; ++i) {
      gld16(kb + koff[i], kl + i * 512);
      gld16(vb + voff[i], vl + i * 512);
    }
    __syncthreads();  // drains vmcnt then barrier

    // S = Q K^T (log2 domain)
    f32x4 sc[4];
#pragma unroll
    for (int nt = 0; nt < 4; ++nt) sc[nt] = (f32x4){0.f, 0.f, 0.f, 0.f};
#pragma unroll
    for (int ks = 0; ks < 4; ++ks) {
      bf16x8 a = qf[ks];
#pragma unroll
      for (int nt = 0; nt < 4; ++nt) {
        bf16x8 bb = *(const bf16x8*)&sK[(nt * 16 + col) * 128 + (((ks * 4 + quad) ^ col) * 8)];
        sc[nt] = mfma16(a, bb, sc[nt]);
      }
    }

    // p = 2^S (fixed ref m=0), mask invalid keys, accumulate l, store P (swizzled A-layout)
    const int key0 = kt * 64;
#pragma unroll
    for (int nt = 0; nt < 4; ++nt) {
      bool valid = (key0 + nt * 16 + col) < L;
#pragma unroll
      for (int r = 0; r < 4; ++r) {
        float p = __builtin_amdgcn_exp2f(sc[nt][r]);
        p = valid ? p : 0.f;
        lsum[r] += p;
        int row = quad * 4 + r;
        int keyc = nt * 16 + col;
        int phys = ((keyc >> 3) ^ (row & 7));
        pw[row * 64 + phys * 8 + (keyc & 7)] = (bf16_t)p;
      }
    }

    // O += P V
#pragma unroll
    for (int ks2 = 0; ks2 < 2; ++ks2) {
      bf16x8 a = *(const bf16x8*)&pw[col * 64 + (((ks2 * 4 + quad) ^ (col & 7)) * 8)];
#pragma unroll
      for (int o = 0; o < 8; ++o) {
        bf16x8 bb = *(const bf16x8*)&sVt[(o * 16 + col) * 64 + (((ks2 * 4 + quad) ^ (col & 7)) * 8)];
        Oacc[o] = mfma16(a, bb, Oacc[o]);
      }
    }
    __syncthreads();
  }

  // reduce l across the 16 cols sharing each row
#pragma unroll
  for (int off = 1; off < 16; off <<= 1)
#pragma unroll
    for (int r = 0; r < 4; ++r) lsum[r] += __shfl_xor(lsum[r], off, 64);

  float* Op = Opart + (size_t)flat * 8192;
#pragma unroll
  for (int o = 0; o < 8; ++o)
#pragma unroll
    for (int r = 0; r < 4; ++r)
      Op[(wave * 16 + quad * 4 + r) * 128 + o * 16 + col] = Oacc[o][r];  // FIX: + wave*16
  if (col == 0) {
#pragma unroll
    for (int r = 0; r < 4; ++r)
      lpart[flat * 64 + wave * 16 + quad * 4 + r] = lsum[r];             // FIX: + wave*16
  }
}

// merge split-K partials + masked-suffix closed form (e^{1e-8} == 1.0f in fp32)
__global__ void combine_kernel(const float* __restrict__ Opart, const float* __restrict__ lpart,
                               const float* __restrict__ sufV, const int* __restrict__ VL,
                               float* __restrict__ Out) {
  int b = blockIdx.x & 15, qt = blockIdx.x >> 4;
  int L = load_valid_len(VL, b);
  int slot0 = qt * 32 + b * 2;
  int t = threadIdx.x;
  int dv = t & 127, rh = t >> 7;
  const float* O0 = Opart + (size_t)slot0 * 8192;
  const float* O1 = O0 + 8192;
  float suf = sufV[b * 128 + dv];
  float wmask = (float)(NK - L);
  float* Ob = Out + ((size_t)b * NQ + qt * 64) * DVV;
  for (int r = rh; r < 64; r += 2) {
    float l = lpart[slot0 * 64 + r] + lpart[slot0 * 64 + 64 + r] + wmask;
    Ob[(size_t)r * 128 + dv] = (O0[r * 128 + dv] + O1[r * 128 + dv] + suf) / l;
  }
}

// ================= fallback path (round-1 kernel) if ws too small =================
#define KSTR 152
#define VSTR 88
#define PSTR 72

__global__ void suffix_fb(const float* __restrict__ V, const int* __restrict__ VL,
                          float* __restrict__ ws) {
  int b = blockIdx.x;
  int kc = blockIdx.y;
  int L = load_valid_len(VL, b);
  int k0 = kc * 128, k1 = k0 + 128;
  int lo = max(L, k0);
  int t = threadIdx.x;
  int dv = t & 127;
  int h = t >> 7;
  float s = 0.f;
  for (int k = lo + h; k < k1; k += 2)
    s += V[((size_t)b * NK + k) * DVV + dv];
  __shared__ float part[128];
  if (h == 0) part[dv] = s;
  __syncthreads();
  if (h == 1) atomicAdd(&ws[b * DVV + dv], part[dv] + s);
}

__launch_bounds__(256, 2)
__global__ void attn_fb(const float* __restrict__ Q, const float* __restrict__ K,
                        const float* __restrict__ V, const int* __restrict__ VL,
                        const float* __restrict__ sufV, float* __restrict__ Out) {
  const int flat = blockIdx.x;
  const int b  = flat & 15;
  const int qt = flat >> 4;
  const int L  = load_valid_len(VL, b);

  __shared__ bf16_t sK2[64 * KSTR];
  __shared__ bf16_t sVT2[128 * VSTR];
  __shared__ bf16_t sP2[4 * 16 * PSTR];

  const int tid  = threadIdx.x;
  const int wave = tid >> 6;
  const int lane = tid & 63;
  const int col  = lane & 15;
  const int quad = lane >> 4;

  const float* Qb = Q + ((size_t)b * NQ + qt * 64 + wave * 16) * DD;
  const float* Kb = K + (size_t)b * NK * DD;
  const float* Vb = V + (size_t)b * NK * DVV;

  bf16x8 qf[4];
  {
    const float scq = 0.08838834764831845f;
    const float* qrow = Qb + (size_t)col * DD + quad * 8;
#pragma unroll
    for (int ks = 0; ks < 4; ++ks) {
      float4 u0 = *(const float4*)(qrow + ks * 32);
      float4 u1 = *(const float4*)(qrow + ks * 32 + 4);
      bf16x8 f;
      f[0] = (bf16_t)(u0.x * scq); f[1] = (bf16_t)(u0.y * scq);
      f[2] = (bf16_t)(u0.z * scq); f[3] = (bf16_t)(u0.w * scq);
      f[4] = (bf16_t)(u1.x * scq); f[5] = (bf16_t)(u1.y * scq);
      f[6] = (bf16_t)(u1.z * scq); f[7] = (bf16_t)(u1.w * scq);
      qf[ks] = f;
    }
  }

  f32x4 Oacc[8];
#pragma unroll
  for (int o = 0; o < 8; ++o) Oacc[o] = (f32x4){0.f, 0.f, 0.f, 0.f};
  float m_i[4], l_i[4];
#pragma unroll
  for (int r = 0; r < 4; ++r) { m_i[r] = -1e30f; l_i[r] = 0.f; }

  const int ktiles = (L + 63) >> 6;
  for (int kt = 0; kt < ktiles; ++kt) {
    {
      int r0 = tid >> 5;
      int d4 = (tid & 31) * 4;
      const float* src = Kb + ((size_t)(kt * 64) + r0) * DD + d4;
#pragma unroll
      for (int i = 0; i < 8; ++i) {
        float4 u = *(const float4*)(src + (size_t)i * 8 * DD);
        bf16x4 w4 = {(bf16_t)u.x, (bf16_t)u.y, (bf16_t)u.z, (bf16_t)u.w};
        *(bf16x4*)&sK2[(r0 + i * 8) * KSTR + d4] = w4;
      }
    }
    {
      int r2 = (tid & 31) * 2;
      int dbase = (tid >> 5) * 4;
#pragma unroll
      for (int i = 0; i < 4; ++i) {
        int d4 = dbase + i * 32;
        const float* s0 = Vb + ((size_t)(kt * 64) + r2) * DVV + d4;
        float4 u0 = *(const float4*)s0;
        float4 u1 = *(const float4*)(s0 + DVV);
        *(bf16x2*)&sVT2[(d4 + 0) * VSTR + r2] = (bf16x2){(bf16_t)u0.x, (bf16_t)u1.x};
        *(bf16x2*)&sVT2[(d4 + 1) * VSTR + r2] = (bf16x2){(bf16_t)u0.y, (bf16_t)u1.y};
        *(bf16x2*)&sVT2[(d4 + 2) * VSTR + r2] = (bf16x2){(bf16_t)u0.z, (bf16_t)u1.z};
        *(bf16x2*)&sVT2[(d4 + 3) * VSTR + r2] = (bf16x2){(bf16_t)u0.w, (bf16_t)u1.w};
      }
    }
    __syncthreads();

    f32x4 sv4[4];
#pragma unroll
    for (int nt = 0; nt < 4; ++nt) sv4[nt] = (f32x4){0.f, 0.f, 0.f, 0.f};
#pragma unroll
    for (int ks = 0; ks < 4; ++ks) {
      bf16x8 a = qf[ks];
#pragma unroll
      for (int nt = 0; nt < 4; ++nt) {
        bf16x8 bb = *(const bf16x8*)&sK2[(nt * 16 + col) * KSTR + ks * 32 + quad * 8];
        sv4[nt] = mfma16(a, bb, sv4[nt]);
      }
    }

    const int key0 = kt * 64;
    float sv[4][4];
    float mloc[4] = {-1e30f, -1e30f, -1e30f, -1e30f};
#pragma unroll
    for (int nt = 0; nt < 4; ++nt) {
      int key = key0 + nt * 16 + col;
      bool valid = key < L;
#pragma unroll
      for (int r = 0; r < 4; ++r) {
        float v = valid ? sv4[nt][r] : -1e30f;
        sv[nt][r] = v;
        mloc[r] = fmaxf(mloc[r], v);
      }
    }
#pragma unroll
    for (int off = 1; off < 16; off <<= 1)
#pragma unroll
      for (int r = 0; r < 4; ++r) mloc[r] = fmaxf(mloc[r], __shfl_xor(mloc[r], off, 64));
    float al[4];
#pragma unroll
    for (int r = 0; r < 4; ++r) {
      float mn = fmaxf(m_i[r], mloc[r]);
      al[r] = __expf(m_i[r] - mn);
      m_i[r] = mn;
    }
    float lloc[4] = {0.f, 0.f, 0.f, 0.f};
#pragma unroll
    for (int nt = 0; nt < 4; ++nt)
#pragma unroll
      for (int r = 0; r < 4; ++r) {
        float p = __expf(sv[nt][r] - m_i[r]);
        sv[nt][r] = p;
        lloc[r] += p;
      }
#pragma unroll
    for (int off = 1; off < 16; off <<= 1)
#pragma unroll
      for (int r = 0; r < 4; ++r) lloc[r] += __shfl_xor(lloc[r], off, 64);
#pragma unroll
    for (int r = 0; r < 4; ++r) l_i[r] = l_i[r] * al[r] + lloc[r];
#pragma unroll
    for (int o = 0; o < 8; ++o)
#pragma unroll
      for (int r = 0; r < 4; ++r) Oacc[o][r] *= al[r];

    bf16_t* pw = &sP2[wave * 16 * PSTR];
#pragma unroll
    for (int nt = 0; nt < 4; ++nt)
#pragma unroll
      for (int r = 0; r < 4; ++r)
        pw[(quad * 4 + r) * PSTR + nt * 16 + col] = (bf16_t)sv[nt][r];

#pragma unroll
    for (int ks2 = 0; ks2 < 2; ++ks2) {
      bf16x8 a = *(const bf16x8*)&pw[(lane & 15) * PSTR + ks2 * 32 + quad * 8];
#pragma unroll
      for (int o = 0; o < 8; ++o) {
        bf16x8 bb = *(const bf16x8*)&sVT2[(o * 16 + col) * VSTR + ks2 * 32 + quad * 8];
        Oacc[o] = mfma16(a, bb, Oacc[o]);
      }
    }
    __syncthreads();
  }

  if (L < NK) {
    const float c = 1e-8f;
    const float w = (float)(NK - L);
    float a2[4], ec[4];
#pragma unroll
    for (int r = 0; r < 4; ++r) {
      float mn = fmaxf(m_i[r], c);
      a2[r] = __expf(m_i[r] - mn);
      ec[r] = __expf(c - mn);
      l_i[r] = l_i[r] * a2[r] + w * ec[r];
    }
    const float* sfv = sufV + b * DVV;
#pragma unroll
    for (int o = 0; o < 8; ++o) {
      float svv = sfv[o * 16 + col];
#pragma unroll
      for (int r = 0; r < 4; ++r) Oacc[o][r] = Oacc[o][r] * a2[r] + ec[r] * svv;
    }
  }

  float invl[4];
#pragma unroll
  for (int r = 0; r < 4; ++r) invl[r] = 1.0f / l_i[r];

  float* Ob = Out + ((size_t)b * NQ + qt * 64 + wave * 16) * DVV;
#pragma unroll
  for (int o = 0; o < 8; ++o)
#pragma unroll
    for (int r = 0; r < 4; ++r)
      Ob[(size_t)(quad * 4 + r) * DVV + o * 16 + col] = Oacc[o][r] * invl[r];
}

extern "C" void kernel_launch(void* const* d_in, const int* in_sizes, int n_in,
                              void* d_out, int out_size, void* d_ws, size_t ws_size,
                              hipStream_t stream) {
  const float* Q  = (const float*)d_in[0];
  const float* K  = (const float*)d_in[1];
  const float* V  = (const float*)d_in[2];
  const int*   VL = (const int*)d_in[3];
  float* out = (float*)d_out;

  if (ws_size >= WS_NEED) {
    char* ws = (char*)d_ws;
    bf16_t* Qb = (bf16_t*)(ws + QB_OFF);
    bf16_t* Kb = (bf16_t*)(ws + KB_OFF);
    bf16_t* Vt = (bf16_t*)(ws + VT_OFF);
    float* sufV = (float*)(ws + SUF_OFF);
    float* Opart = (float*)(ws + OP_OFF);
    float* lpart = (float*)(ws + LP_OFF);

    hipMemsetAsync(sufV, 0, BATCH * DVV * sizeof(float), stream);
    convqk_kernel<<<1024, 256, 0, stream>>>(Q, K, Qb, Kb);
    vtrans_kernel<<<BATCH * (NK / 64), 256, 0, stream>>>(V, VL, Vt, sufV);
    attn_kernel<<<BATCH * (NQ / 64) * 2, 256, 0, stream>>>(Qb, Kb, Vt, VL, Opart, lpart);
    combine_kernel<<<BATCH * (NQ / 64), 256, 0, stream>>>(Opart, lpart, sufV, VL, out);
  } else {
    float* ws = (float*)d_ws;
    hipMemsetAsync(ws, 0, BATCH * DVV * sizeof(float), stream);
    dim3 g1(BATCH, 16);
    suffix_fb<<<g1, 256, 0, stream>>>(V, VL, ws);
    attn_fb<<<BATCH * (NQ / 64), 256, 0, stream>>>(Q, K, V, VL, ws, out);
  }
}

// Round 4
// 164.223 us; speedup vs baseline: 1.1703x; 1.0916x over previous
//
#include <hip/hip_runtime.h>
#include <stdint.h>

#define BATCH 16
#define NQ    2048
#define NK    2048
#define DD    128
#define DVV   128

typedef __bf16 bf16_t;
typedef __bf16 bf16x2 __attribute__((ext_vector_type(2)));
typedef __bf16 bf16x4 __attribute__((ext_vector_type(4)));
typedef __bf16 bf16x8 __attribute__((ext_vector_type(8)));
typedef float  f32x4  __attribute__((ext_vector_type(4)));

// ---------------- ws layout (bytes) ----------------
#define QB_OFF  ((size_t)0)                       // bf16 Q, scaled by log2e/sqrt(128): 8 MB
#define KB_OFF  ((size_t)8 * 1024 * 1024)         // bf16 K: 8 MB
#define VT_OFF  ((size_t)16 * 1024 * 1024)        // bf16 V^T [b][dv][k]: 8 MB
#define SUF_OFF ((size_t)24 * 1024 * 1024)        // fp32 sufV[b][dv]: 8 KB
#define OP_OFF  (SUF_OFF + 65536)                 // fp32 O partials: 1024 * 8192 * 4 = 32 MB
#define LP_OFF  (OP_OFF + (size_t)1024 * 8192 * 4)// fp32 l partials: 1024 * 64 * 4
#define WS_NEED (LP_OFF + (size_t)1024 * 64 * 4)

__device__ __forceinline__ int load_valid_len(const int* VL, int b) {
  bool looks64 = true;
#pragma unroll
  for (int i = 0; i < 16; ++i) {
    int hi = VL[2 * i + 1];
    unsigned lo = (unsigned)VL[2 * i];
    looks64 = looks64 && (hi == 0) && (lo <= 2048u);
  }
  int L = looks64 ? VL[2 * b] : VL[b];
  return min(max(L, 0), NK);
}

__device__ __forceinline__ void gld16(const void* g, void* l) {
  __builtin_amdgcn_global_load_lds(
      (const __attribute__((address_space(1))) unsigned int*)g,
      (__attribute__((address_space(3))) unsigned int*)l, 16, 0, 0);
}

__device__ __forceinline__ f32x4 mfma16(bf16x8 a, bf16x8 b, f32x4 c) {
  return __builtin_amdgcn_mfma_f32_16x16x32_bf16(a, b, c, 0, 0, 0);
}

// ---------------- fused preprocessing ----------------
// blocks 0..1023 : Q,K fp32 -> bf16 (Q scaled by log2e/sqrt(128))
// blocks 1024..1535 : V fp32 [b][k][dv] -> bf16 V^T [b][dv][k] + suffix sums (shuffle-reduced)
__global__ void prep_kernel(const float* __restrict__ Q, const float* __restrict__ K,
                            const float* __restrict__ V, const int* __restrict__ VL,
                            bf16_t* __restrict__ Qb, bf16_t* __restrict__ Kb,
                            bf16_t* __restrict__ Vt, float* __restrict__ sufV) {
  __shared__ bf16_t tile[128 * 72];  // [dv][key] stride 72 (144B rows, 16B-aligned)
  const int bid = blockIdx.x;
  const int t = threadIdx.x;
  if (bid < 1024) {
    const float sc = 0.1275174307f;  // log2(e)/sqrt(128)
    size_t base = ((size_t)bid * 256 + t) * 32;
    const size_t NQK = (size_t)BATCH * NQ * DD;  // 4194304
    bool isQ = base < NQK;
    const float* src = isQ ? (Q + base) : (K + (base - NQK));
    bf16_t* dst = isQ ? (Qb + base) : (Kb + (base - NQK));
    float s = isQ ? sc : 1.0f;
#pragma unroll
    for (int i = 0; i < 4; ++i) {
      float4 a = ((const float4*)src)[i * 2];
      float4 b = ((const float4*)src)[i * 2 + 1];
      bf16x8 o;
      o[0] = (bf16_t)(a.x * s); o[1] = (bf16_t)(a.y * s);
      o[2] = (bf16_t)(a.z * s); o[3] = (bf16_t)(a.w * s);
      o[4] = (bf16_t)(b.x * s); o[5] = (bf16_t)(b.y * s);
      o[6] = (bf16_t)(b.z * s); o[7] = (bf16_t)(b.w * s);
      ((bf16x8*)dst)[i] = o;
    }
    return;
  }
  // ---- vtrans part ----
  int v = bid - 1024;
  int b = v & 15, kt = v >> 4;
  int L = load_valid_len(VL, b);
  int m = t & 31;   // key-pair index 0..31
  int g = t >> 5;   // dv group 0..7
  int r2 = m * 2;
  int k0g = kt * 64 + r2;
  const float* src = V + ((size_t)b * NK + k0g) * DVV;
  float sacc[4][4];
#pragma unroll
  for (int i = 0; i < 4; ++i)
#pragma unroll
    for (int j = 0; j < 4; ++j) sacc[i][j] = 0.f;
  bool a0 = (k0g >= L), a1 = (k0g + 1 >= L);
#pragma unroll
  for (int i = 0; i < 4; ++i) {
    int d4 = g * 4 + i * 32;
    float4 u0 = *(const float4*)(src + d4);
    float4 u1 = *(const float4*)(src + DVV + d4);
    *(bf16x2*)&tile[(d4 + 0) * 72 + r2] = (bf16x2){(bf16_t)u0.x, (bf16_t)u1.x};
    *(bf16x2*)&tile[(d4 + 1) * 72 + r2] = (bf16x2){(bf16_t)u0.y, (bf16_t)u1.y};
    *(bf16x2*)&tile[(d4 + 2) * 72 + r2] = (bf16x2){(bf16_t)u0.z, (bf16_t)u1.z};
    *(bf16x2*)&tile[(d4 + 3) * 72 + r2] = (bf16x2){(bf16_t)u0.w, (bf16_t)u1.w};
    if (a0) { sacc[i][0] += u0.x; sacc[i][1] += u0.y; sacc[i][2] += u0.z; sacc[i][3] += u0.w; }
    if (a1) { sacc[i][0] += u1.x; sacc[i][1] += u1.y; sacc[i][2] += u1.z; sacc[i][3] += u1.w; }
  }
  __syncthreads();
  // suffix reduce across the 32 lanes of each dv-group (stays within wave halves)
#pragma unroll
  for (int off = 1; off < 32; off <<= 1)
#pragma unroll
    for (int i = 0; i < 4; ++i)
#pragma unroll
      for (int j = 0; j < 4; ++j) sacc[i][j] += __shfl_xor(sacc[i][j], off, 64);
  if (m == 0) {
#pragma unroll
    for (int i = 0; i < 4; ++i)
#pragma unroll
      for (int j = 0; j < 4; ++j)
        atomicAdd(&sufV[b * 128 + g * 4 + i * 32 + j], sacc[i][j]);
  }
  // coalesced transposed write
  int dv = t >> 1, half = t & 1;
  bf16_t* dst = Vt + (size_t)b * DVV * NK + (size_t)dv * NK + kt * 64 + half * 32;
  const bf16_t* srow = &tile[dv * 72 + half * 32];
#pragma unroll
  for (int j = 0; j < 4; ++j)
    *(bf16x8*)(dst + j * 8) = *(const bf16x8*)(srow + j * 8);
}

// ---------------- main attention (split-K, fixed ref m=0, log2 domain, dbuf pipeline) ----------------
// LDS: sK 2x16KB + sVt 2x16KB + sP 8KB = 72KB -> 2 blocks/CU.
__launch_bounds__(256, 2)
__global__ void attn_kernel(const bf16_t* __restrict__ Qb, const bf16_t* __restrict__ Kb,
                            const bf16_t* __restrict__ Vt, const int* __restrict__ VL,
                            float* __restrict__ Opart, float* __restrict__ lpart) {
  __shared__ bf16_t sK[2][64 * 128];
  __shared__ bf16_t sVt[2][128 * 64];
  __shared__ bf16_t sP[4][16 * 64];

  const int flat = blockIdx.x;
  const int s  = flat & 1;
  const int b  = (flat >> 1) & 15;
  const int qt = flat >> 5;
  const int L  = load_valid_len(VL, b);
  const int ktiles = (L + 63) >> 6;
  const int t0 = (s * ktiles) >> 1;
  const int t1 = ((s + 1) * ktiles) >> 1;

  const int tid = threadIdx.x;
  const int wave = tid >> 6;
  const int lane = tid & 63;
  const int col = lane & 15;
  const int quad = lane >> 4;

  // Q fragments (already bf16, scaled, log2 domain)
  bf16x8 qf[4];
  {
    const bf16_t* qrow = Qb + ((size_t)b * NQ + qt * 64 + wave * 16 + col) * DD + quad * 8;
#pragma unroll
    for (int ks = 0; ks < 4; ++ks) qf[ks] = *(const bf16x8*)(qrow + ks * 32);
  }

  const char* Kbyte = (const char*)Kb + (size_t)b * NK * DD * 2;
  const char* Vbyte = (const char*)Vt + (size_t)b * DVV * NK * 2;
  int koff[4], voff[4];
#pragma unroll
  for (int i = 0; i < 4; ++i) {
    int krow = wave * 16 + i * 4 + (lane >> 4);
    koff[i] = krow * 256 + (((lane & 15) ^ (krow & 15)) * 16);
    int vrow = wave * 32 + i * 8 + (lane >> 3);
    voff[i] = vrow * (NK * 2) + (((lane & 7) ^ ((lane >> 3) & 7)) * 16);
  }
  bf16_t* pw = sP[wave];

  f32x4 Oacc[8];
#pragma unroll
  for (int o = 0; o < 8; ++o) Oacc[o] = (f32x4){0.f, 0.f, 0.f, 0.f};
  float lsum[4] = {0.f, 0.f, 0.f, 0.f};

  auto issueTile = [&](int kt, int bufi) {
    const char* kb = Kbyte + (size_t)kt * 16384;
    const char* vb = Vbyte + (size_t)kt * 128;
    bf16_t* kl = &sK[bufi][wave * 2048];
    bf16_t* vl = &sVt[bufi][wave * 2048];
#pragma unroll
    for (int i = 0; i < 4; ++i) {
      gld16(kb + koff[i], kl + i * 512);
      gld16(vb + voff[i], vl + i * 512);
    }
  };

  if (t0 < t1) issueTile(t0, 0);
  int bufi = 0;
  for (int kt = t0; kt < t1; ++kt) {
    if (kt + 1 < t1) {
      issueTile(kt + 1, bufi ^ 1);
      // wait only the 8 oldest loads (this tile's); prefetch stays in flight
      asm volatile("s_waitcnt vmcnt(8)\n\ts_barrier" ::: "memory");
    } else {
      asm volatile("s_waitcnt vmcnt(0)\n\ts_barrier" ::: "memory");
    }

    const bf16_t* kb_ = sK[bufi];
    const bf16_t* vb_ = sVt[bufi];

    // S = Q K^T (log2 domain)
    f32x4 sc[4];
#pragma unroll
    for (int nt = 0; nt < 4; ++nt) sc[nt] = (f32x4){0.f, 0.f, 0.f, 0.f};
#pragma unroll
    for (int ks = 0; ks < 4; ++ks) {
      bf16x8 a = qf[ks];
#pragma unroll
      for (int nt = 0; nt < 4; ++nt) {
        bf16x8 bb = *(const bf16x8*)&kb_[(nt * 16 + col) * 128 + (((ks * 4 + quad) ^ col) * 8)];
        sc[nt] = mfma16(a, bb, sc[nt]);
      }
    }

    // p = 2^S, mask invalid keys, accumulate l, store P (swizzled A-layout)
    const int key0 = kt * 64;
#pragma unroll
    for (int nt = 0; nt < 4; ++nt) {
      bool valid = (key0 + nt * 16 + col) < L;
#pragma unroll
      for (int r = 0; r < 4; ++r) {
        float p = __builtin_amdgcn_exp2f(sc[nt][r]);
        p = valid ? p : 0.f;
        lsum[r] += p;
        int row = quad * 4 + r;
        int keyc = nt * 16 + col;
        int phys = ((keyc >> 3) ^ (row & 7));
        pw[row * 64 + phys * 8 + (keyc & 7)] = (bf16_t)p;
      }
    }

    // O += P V
#pragma unroll
    for (int ks2 = 0; ks2 < 2; ++ks2) {
      bf16x8 a = *(const bf16x8*)&pw[col * 64 + (((ks2 * 4 + quad) ^ (col & 7)) * 8)];
#pragma unroll
      for (int o = 0; o < 8; ++o) {
        bf16x8 bb = *(const bf16x8*)&vb_[(o * 16 + col) * 64 + (((ks2 * 4 + quad) ^ (col & 7)) * 8)];
        Oacc[o] = mfma16(a, bb, Oacc[o]);
      }
    }
    asm volatile("s_barrier" ::: "memory");  // buffer-reuse fence (no vm drain)
    bufi ^= 1;
  }

  // reduce l across the 16 cols sharing each row
#pragma unroll
  for (int off = 1; off < 16; off <<= 1)
#pragma unroll
    for (int r = 0; r < 4; ++r) lsum[r] += __shfl_xor(lsum[r], off, 64);

  float* Op = Opart + (size_t)flat * 8192;
#pragma unroll
  for (int o = 0; o < 8; ++o)
#pragma unroll
    for (int r = 0; r < 4; ++r)
      Op[(wave * 16 + quad * 4 + r) * 128 + o * 16 + col] = Oacc[o][r];
  if (col == 0) {
#pragma unroll
    for (int r = 0; r < 4; ++r)
      lpart[flat * 64 + wave * 16 + quad * 4 + r] = lsum[r];
  }
}

// merge split-K partials + masked-suffix closed form (e^{1e-8} == 1.0f in fp32)
__global__ void combine_kernel(const float* __restrict__ Opart, const float* __restrict__ lpart,
                               const float* __restrict__ sufV, const int* __restrict__ VL,
                               float* __restrict__ Out) {
  int b = blockIdx.x & 15, qt = blockIdx.x >> 4;
  int L = load_valid_len(VL, b);
  int slot0 = qt * 32 + b * 2;
  int t = threadIdx.x;
  int dv = t & 127, rh = t >> 7;
  const float* O0 = Opart + (size_t)slot0 * 8192;
  const float* O1 = O0 + 8192;
  float suf = sufV[b * 128 + dv];
  float wmask = (float)(NK - L);
  float* Ob = Out + ((size_t)b * NQ + qt * 64) * DVV;
  for (int r = rh; r < 64; r += 2) {
    float l = lpart[slot0 * 64 + r] + lpart[slot0 * 64 + 64 + r] + wmask;
    Ob[(size_t)r * 128 + dv] = (O0[r * 128 + dv] + O1[r * 128 + dv] + suf) / l;
  }
}

// ================= fallback path (round-1 kernel) if ws too small =================
#define KSTR 152
#define VSTR 88
#define PSTR 72

__global__ void suffix_fb(const float* __restrict__ V, const int* __restrict__ VL,
                          float* __restrict__ ws) {
  int b = blockIdx.x;
  int kc = blockIdx.y;
  int L = load_valid_len(VL, b);
  int k0 = kc * 128, k1 = k0 + 128;
  int lo = max(L, k0);
  int t = threadIdx.x;
  int dv = t & 127;
  int h = t >> 7;
  float s = 0.f;
  for (int k = lo + h; k < k1; k += 2)
    s += V[((size_t)b * NK + k) * DVV + dv];
  __shared__ float part[128];
  if (h == 0) part[dv] = s;
  __syncthreads();
  if (h == 1) atomicAdd(&ws[b * DVV + dv], part[dv] + s);
}

__launch_bounds__(256, 2)
__global__ void attn_fb(const float* __restrict__ Q, const float* __restrict__ K,
                        const float* __restrict__ V, const int* __restrict__ VL,
                        const float* __restrict__ sufV, float* __restrict__ Out) {
  const int flat = blockIdx.x;
  const int b  = flat & 15;
  const int qt = flat >> 4;
  const int L  = load_valid_len(VL, b);

  __shared__ bf16_t sK2[64 * KSTR];
  __shared__ bf16_t sVT2[128 * VSTR];
  __shared__ bf16_t sP2[4 * 16 * PSTR];

  const int tid  = threadIdx.x;
  const int wave = tid >> 6;
  const int lane = tid & 63;
  const int col  = lane & 15;
  const int quad = lane >> 4;

  const float* Qb = Q + ((size_t)b * NQ + qt * 64 + wave * 16) * DD;
  const float* Kb = K + (size_t)b * NK * DD;
  const float* Vb = V + (size_t)b * NK * DVV;

  bf16x8 qf[4];
  {
    const float scq = 0.08838834764831845f;
    const float* qrow = Qb + (size_t)col * DD + quad * 8;
#pragma unroll
    for (int ks = 0; ks < 4; ++ks) {
      float4 u0 = *(const float4*)(qrow + ks * 32);
      float4 u1 = *(const float4*)(qrow + ks * 32 + 4);
      bf16x8 f;
      f[0] = (bf16_t)(u0.x * scq); f[1] = (bf16_t)(u0.y * scq);
      f[2] = (bf16_t)(u0.z * scq); f[3] = (bf16_t)(u0.w * scq);
      f[4] = (bf16_t)(u1.x * scq); f[5] = (bf16_t)(u1.y * scq);
      f[6] = (bf16_t)(u1.z * scq); f[7] = (bf16_t)(u1.w * scq);
      qf[ks] = f;
    }
  }

  f32x4 Oacc[8];
#pragma unroll
  for (int o = 0; o < 8; ++o) Oacc[o] = (f32x4){0.f, 0.f, 0.f, 0.f};
  float m_i[4], l_i[4];
#pragma unroll
  for (int r = 0; r < 4; ++r) { m_i[r] = -1e30f; l_i[r] = 0.f; }

  const int ktiles = (L + 63) >> 6;
  for (int kt = 0; kt < ktiles; ++kt) {
    {
      int r0 = tid >> 5;
      int d4 = (tid & 31) * 4;
      const float* src = Kb + ((size_t)(kt * 64) + r0) * DD + d4;
#pragma unroll
      for (int i = 0; i < 8; ++i) {
        float4 u = *(const float4*)(src + (size_t)i * 8 * DD);
        bf16x4 w4 = {(bf16_t)u.x, (bf16_t)u.y, (bf16_t)u.z, (bf16_t)u.w};
        *(bf16x4*)&sK2[(r0 + i * 8) * KSTR + d4] = w4;
      }
    }
    {
      int r2 = (tid & 31) * 2;
      int dbase = (tid >> 5) * 4;
#pragma unroll
      for (int i = 0; i < 4; ++i) {
        int d4 = dbase + i * 32;
        const float* s0 = Vb + ((size_t)(kt * 64) + r2) * DVV + d4;
        float4 u0 = *(const float4*)s0;
        float4 u1 = *(const float4*)(s0 + DVV);
        *(bf16x2*)&sVT2[(d4 + 0) * VSTR + r2] = (bf16x2){(bf16_t)u0.x, (bf16_t)u1.x};
        *(bf16x2*)&sVT2[(d4 + 1) * VSTR + r2] = (bf16x2){(bf16_t)u0.y, (bf16_t)u1.y};
        *(bf16x2*)&sVT2[(d4 + 2) * VSTR + r2] = (bf16x2){(bf16_t)u0.z, (bf16_t)u1.z};
        *(bf16x2*)&sVT2[(d4 + 3) * VSTR + r2] = (bf16x2){(bf16_t)u0.w, (bf16_t)u1.w};
      }
    }
    __syncthreads();

    f32x4 sv4[4];
#pragma unroll
    for (int nt = 0; nt < 4; ++nt) sv4[nt] = (f32x4){0.f, 0.f, 0.f, 0.f};
#pragma unroll
    for (int ks = 0; ks < 4; ++ks) {
      bf16x8 a = qf[ks];
#pragma unroll
      for (int nt = 0; nt < 4; ++nt) {
        bf16x8 bb = *(const bf16x8*)&sK2[(nt * 16 + col) * KSTR + ks * 32 + quad * 8];
        sv4[nt] = mfma16(a, bb, sv4[nt]);
      }
    }

    const int key0 = kt * 64;
    float sv[4][4];
    float mloc[4] = {-1e30f, -1e30f, -1e30f, -1e30f};
#pragma unroll
    for (int nt = 0; nt < 4; ++nt) {
      int key = key0 + nt * 16 + col;
      bool valid = key < L;
#pragma unroll
      for (int r = 0; r < 4; ++r) {
        float v = valid ? sv4[nt][r] : -1e30f;
        sv[nt][r] = v;
        mloc[r] = fmaxf(mloc[r], v);
      }
    }
#pragma unroll
    for (int off = 1; off < 16; off <<= 1)
#pragma unroll
      for (int r = 0; r < 4; ++r) mloc[r] = fmaxf(mloc[r], __shfl_xor(mloc[r], off, 64));
    float al[4];
#pragma unroll
    for (int r = 0; r < 4; ++r) {
      float mn = fmaxf(m_i[r], mloc[r]);
      al[r] = __expf(m_i[r] - mn);
      m_i[r] = mn;
    }
    float lloc[4] = {0.f, 0.f, 0.f, 0.f};
#pragma unroll
    for (int nt = 0; nt < 4; ++nt)
#pragma unroll
      for (int r = 0; r < 4; ++r) {
        float p = __expf(sv[nt][r] - m_i[r]);
        sv[nt][r] = p;
        lloc[r] += p;
      }
#pragma unroll
    for (int off = 1; off < 16; off <<= 1)
#pragma unroll
      for (int r = 0; r < 4; ++r) lloc[r] += __shfl_xor(lloc[r], off, 64);
#pragma unroll
    for (int r = 0; r < 4; ++r) l_i[r] = l_i[r] * al[r] + lloc[r];
#pragma unroll
    for (int o = 0; o < 8; ++o)
#pragma unroll
      for (int r = 0; r < 4; ++r) Oacc[o][r] *= al[r];

    bf16_t* pw = &sP2[wave * 16 * PSTR];
#pragma unroll
    for (int nt = 0; nt < 4; ++nt)
#pragma unroll
      for (int r = 0; r < 4; ++r)
        pw[(quad * 4 + r) * PSTR + nt * 16 + col] = (bf16_t)sv[nt][r];

#pragma unroll
    for (int ks2 = 0; ks2 < 2; ++ks2) {
      bf16x8 a = *(const bf16x8*)&pw[(lane & 15) * PSTR + ks2 * 32 + quad * 8];
#pragma unroll
      for (int o = 0; o < 8; ++o) {
        bf16x8 bb = *(const bf16x8*)&sVT2[(o * 16 + col) * VSTR + ks2 * 32 + quad * 8];
        Oacc[o] = mfma16(a, bb, Oacc[o]);
      }
    }
    __syncthreads();
  }

  if (L < NK) {
    const float c = 1e-8f;
    const float w = (float)(NK - L);
    float a2[4], ec[4];
#pragma unroll
    for (int r = 0; r < 4; ++r) {
      float mn = fmaxf(m_i[r], c);
      a2[r] = __expf(m_i[r] - mn);
      ec[r] = __expf(c - mn);
      l_i[r] = l_i[r] * a2[r] + w * ec[r];
    }
    const float* sfv = sufV + b * DVV;
#pragma unroll
    for (int o = 0; o < 8; ++o) {
      float svv = sfv[o * 16 + col];
#pragma unroll
      for (int r = 0; r < 4; ++r) Oacc[o][r] = Oacc[o][r] * a2[r] + ec[r] * svv;
    }
  }

  float invl[4];
#pragma unroll
  for (int r = 0; r < 4; ++r) invl[r] = 1.0f / l_i[r];

  float* Ob = Out + ((size_t)b * NQ + qt * 64 + wave * 16) * DVV;
#pragma unroll
  for (int o = 0; o < 8; ++o)
#pragma unroll
    for (int r = 0; r < 4; ++r)
      Ob[(size_t)(quad * 4 + r) * DVV + o * 16 + col] = Oacc[o][r] * invl[r];
}

extern "C" void kernel_launch(void* const* d_in, const int* in_sizes, int n_in,
                              void* d_out, int out_size, void* d_ws, size_t ws_size,
                              hipStream_t stream) {
  const float* Q  = (const float*)d_in[0];
  const float* K  = (const float*)d_in[1];
  const float* V  = (const float*)d_in[2];
  const int*   VL = (const int*)d_in[3];
  float* out = (float*)d_out;

  if (ws_size >= WS_NEED) {
    char* ws = (char*)d_ws;
    bf16_t* Qb = (bf16_t*)(ws + QB_OFF);
    bf16_t* Kb = (bf16_t*)(ws + KB_OFF);
    bf16_t* Vt = (bf16_t*)(ws + VT_OFF);
    float* sufV = (float*)(ws + SUF_OFF);
    float* Opart = (float*)(ws + OP_OFF);
    float* lpart = (float*)(ws + LP_OFF);

    hipMemsetAsync(sufV, 0, BATCH * DVV * sizeof(float), stream);
    prep_kernel<<<1536, 256, 0, stream>>>(Q, K, V, VL, Qb, Kb, Vt, sufV);
    attn_kernel<<<BATCH * (NQ / 64) * 2, 256, 0, stream>>>(Qb, Kb, Vt, VL, Opart, lpart);
    combine_kernel<<<BATCH * (NQ / 64), 256, 0, stream>>>(Opart, lpart, sufV, VL, out);
  } else {
    float* ws = (float*)d_ws;
    hipMemsetAsync(ws, 0, BATCH * DVV * sizeof(float), stream);
    dim3 g1(BATCH, 16);
    suffix_fb<<<g1, 256, 0, stream>>>(V, VL, ws);
    attn_fb<<<BATCH * (NQ / 64), 256, 0, stream>>>(Q, K, V, VL, ws, out);
  }
}

// Round 5
// 147.395 us; speedup vs baseline: 1.3039x; 1.1142x over previous
//
#include <hip/hip_runtime.h>
#include <stdint.h>

#define BATCH 16
#define NQ    2048
#define NK    2048
#define DD    128
#define DVV   128

typedef __bf16 bf16_t;
typedef __bf16 bf16x2 __attribute__((ext_vector_type(2)));
typedef __bf16 bf16x4 __attribute__((ext_vector_type(4)));
typedef __bf16 bf16x8 __attribute__((ext_vector_type(8)));
typedef float  f32x4  __attribute__((ext_vector_type(4)));

// ---------------- ws layout (bytes) ----------------
#define QB_OFF   ((size_t)0)                 // bf16 Q scaled by log2e/sqrt(128): 8 MB
#define KB_OFF   ((size_t)8 * 1024 * 1024)   // bf16 K: 8 MB
#define VT_OFF   ((size_t)16 * 1024 * 1024)  // bf16 V^T [b][dv][k]: 8 MB
#define SUF_OFF  ((size_t)24 * 1024 * 1024)  // fp32 sufV[b][dv]: 8 KB
#define SCH_OFF  (SUF_OFF + 65536)           // int schedule[512]
#define WS_NEED  (SCH_OFF + 4096)

__device__ __forceinline__ int load_valid_len(const int* VL, int b) {
  bool looks64 = true;
#pragma unroll
  for (int i = 0; i < 16; ++i) {
    int hi = VL[2 * i + 1];
    unsigned lo = (unsigned)VL[2 * i];
    looks64 = looks64 && (hi == 0) && (lo <= 2048u);
  }
  int L = looks64 ? VL[2 * b] : VL[b];
  return min(max(L, 0), NK);
}

__device__ __forceinline__ void gld16(const void* g, void* l) {
  __builtin_amdgcn_global_load_lds(
      (const __attribute__((address_space(1))) unsigned int*)g,
      (__attribute__((address_space(3))) unsigned int*)l, 16, 0, 0);
}

__device__ __forceinline__ f32x4 mfma16(bf16x8 a, bf16x8 b, f32x4 c) {
  return __builtin_amdgcn_mfma_f32_16x16x32_bf16(a, b, c, 0, 0, 0);
}

// ---------------- fused preprocessing ----------------
// blocks 0..1023   : Q,K fp32 -> bf16 (Q scaled by log2e/sqrt(128))
// blocks 1024..1535: V fp32 [b][k][dv] -> bf16 V^T [b][dv][k] + suffix sums
// block 1536       : snake schedule (batches sorted by L desc, rank j paired with 511-j)
__global__ void prep_kernel(const float* __restrict__ Q, const float* __restrict__ K,
                            const float* __restrict__ V, const int* __restrict__ VL,
                            bf16_t* __restrict__ Qb, bf16_t* __restrict__ Kb,
                            bf16_t* __restrict__ Vt, float* __restrict__ sufV,
                            int* __restrict__ sched) {
  __shared__ bf16_t tile[128 * 72];  // [dv][key] stride 72
  __shared__ int bs[16];
  const int bid = blockIdx.x;
  const int t = threadIdx.x;
  if (bid < 1024) {
    const float sc = 0.1275174307f;  // log2(e)/sqrt(128)
    size_t base = ((size_t)bid * 256 + t) * 32;
    const size_t NQK = (size_t)BATCH * NQ * DD;
    bool isQ = base < NQK;
    const float* src = isQ ? (Q + base) : (K + (base - NQK));
    bf16_t* dst = isQ ? (Qb + base) : (Kb + (base - NQK));
    float s = isQ ? sc : 1.0f;
#pragma unroll
    for (int i = 0; i < 4; ++i) {
      float4 a = ((const float4*)src)[i * 2];
      float4 b = ((const float4*)src)[i * 2 + 1];
      bf16x8 o;
      o[0] = (bf16_t)(a.x * s); o[1] = (bf16_t)(a.y * s);
      o[2] = (bf16_t)(a.z * s); o[3] = (bf16_t)(a.w * s);
      o[4] = (bf16_t)(b.x * s); o[5] = (bf16_t)(b.y * s);
      o[6] = (bf16_t)(b.z * s); o[7] = (bf16_t)(b.w * s);
      ((bf16x8*)dst)[i] = o;
    }
    return;
  }
  if (bid < 1536) {
    // ---- vtrans ----
    int v = bid - 1024;
    int b = v & 15, kt = v >> 4;
    int L = load_valid_len(VL, b);
    int m = t & 31;   // key-pair 0..31
    int g = t >> 5;   // dv group 0..7
    int r2 = m * 2;
    int k0g = kt * 64 + r2;
    const float* src = V + ((size_t)b * NK + k0g) * DVV;
    float sacc[4][4];
#pragma unroll
    for (int i = 0; i < 4; ++i)
#pragma unroll
      for (int j = 0; j < 4; ++j) sacc[i][j] = 0.f;
    bool a0 = (k0g >= L), a1 = (k0g + 1 >= L);
#pragma unroll
    for (int i = 0; i < 4; ++i) {
      int d4 = g * 4 + i * 32;
      float4 u0 = *(const float4*)(src + d4);
      float4 u1 = *(const float4*)(src + DVV + d4);
      *(bf16x2*)&tile[(d4 + 0) * 72 + r2] = (bf16x2){(bf16_t)u0.x, (bf16_t)u1.x};
      *(bf16x2*)&tile[(d4 + 1) * 72 + r2] = (bf16x2){(bf16_t)u0.y, (bf16_t)u1.y};
      *(bf16x2*)&tile[(d4 + 2) * 72 + r2] = (bf16x2){(bf16_t)u0.z, (bf16_t)u1.z};
      *(bf16x2*)&tile[(d4 + 3) * 72 + r2] = (bf16x2){(bf16_t)u0.w, (bf16_t)u1.w};
      if (a0) { sacc[i][0] += u0.x; sacc[i][1] += u0.y; sacc[i][2] += u0.z; sacc[i][3] += u0.w; }
      if (a1) { sacc[i][0] += u1.x; sacc[i][1] += u1.y; sacc[i][2] += u1.z; sacc[i][3] += u1.w; }
    }
    __syncthreads();
#pragma unroll
    for (int off = 1; off < 32; off <<= 1)
#pragma unroll
      for (int i = 0; i < 4; ++i)
#pragma unroll
        for (int j = 0; j < 4; ++j) sacc[i][j] += __shfl_xor(sacc[i][j], off, 64);
    if (m == 0) {
#pragma unroll
      for (int i = 0; i < 4; ++i)
#pragma unroll
        for (int j = 0; j < 4; ++j)
          atomicAdd(&sufV[b * 128 + g * 4 + i * 32 + j], sacc[i][j]);
    }
    int dv = t >> 1, half = t & 1;
    bf16_t* dst = Vt + (size_t)b * DVV * NK + (size_t)dv * NK + kt * 64 + half * 32;
    const bf16_t* srow = &tile[dv * 72 + half * 32];
#pragma unroll
    for (int j = 0; j < 4; ++j)
      *(bf16x8*)(dst + j * 8) = *(const bf16x8*)(srow + j * 8);
    return;
  }
  // ---- schedule block ----
  if (t == 0) {
    int Ls[16], idx[16];
#pragma unroll
    for (int i = 0; i < 16; ++i) { Ls[i] = load_valid_len(VL, i); idx[i] = i; }
    for (int i = 1; i < 16; ++i) {       // insertion sort desc by L
      int lv = Ls[i], iv = idx[i], j = i - 1;
      while (j >= 0 && Ls[j] < lv) { Ls[j + 1] = Ls[j]; idx[j + 1] = idx[j]; --j; }
      Ls[j + 1] = lv; idx[j + 1] = iv;
    }
#pragma unroll
    for (int i = 0; i < 16; ++i) bs[i] = idx[i];
  }
  __syncthreads();
  for (int j = t; j < 512; j += 256) {
    int r = (j < 256) ? j : (767 - j);    // snake pairing: blocks j, j+256 share a CU slot
    sched[j] = (bs[r >> 5] << 5) | (r & 31);
  }
}

// ---------------- main attention (schedule-driven, fixed ref m=0, log2 domain, direct out) ---
// LDS: sK 2x16KB + sVt 2x16KB + sP 8KB = 72KB -> 2 blocks/CU.
__launch_bounds__(256, 2)
__global__ void attn_kernel(const bf16_t* __restrict__ Qb, const bf16_t* __restrict__ Kb,
                            const bf16_t* __restrict__ Vt, const int* __restrict__ VL,
                            const float* __restrict__ sufV, const int* __restrict__ sched,
                            float* __restrict__ Out) {
  __shared__ bf16_t sK[2][64 * 128];
  __shared__ bf16_t sVt[2][128 * 64];
  __shared__ bf16_t sP[4][16 * 64];

  const int unit = sched[blockIdx.x];
  const int b  = (unit >> 5) & 15;
  const int qt = unit & 31;
  const int L  = load_valid_len(VL, b);
  const int ktiles = (L + 63) >> 6;

  const int tid = threadIdx.x;
  const int wave = tid >> 6;
  const int lane = tid & 63;
  const int col = lane & 15;
  const int quad = lane >> 4;

  // Q fragments (already bf16, scaled, log2 domain)
  bf16x8 qf[4];
  {
    const bf16_t* qrow = Qb + ((size_t)b * NQ + qt * 64 + wave * 16 + col) * DD + quad * 8;
#pragma unroll
    for (int ks = 0; ks < 4; ++ks) qf[ks] = *(const bf16x8*)(qrow + ks * 32);
  }

  const char* Kbyte = (const char*)Kb + (size_t)b * NK * DD * 2;
  const char* Vbyte = (const char*)Vt + (size_t)b * DVV * NK * 2;
  int koff[4], voff[4];
#pragma unroll
  for (int i = 0; i < 4; ++i) {
    int krow = wave * 16 + i * 4 + (lane >> 4);
    koff[i] = krow * 256 + (((lane & 15) ^ (krow & 15)) * 16);
    int vrow = wave * 32 + i * 8 + (lane >> 3);
    voff[i] = vrow * (NK * 2) + (((lane & 7) ^ ((lane >> 3) & 7)) * 16);
  }
  bf16_t* pw = sP[wave];

  f32x4 Oacc[8];
#pragma unroll
  for (int o = 0; o < 8; ++o) Oacc[o] = (f32x4){0.f, 0.f, 0.f, 0.f};
  float lsum[4] = {0.f, 0.f, 0.f, 0.f};

  auto issueTile = [&](int kt, int bufi) {
    const char* kb = Kbyte + (size_t)kt * 16384;
    const char* vb = Vbyte + (size_t)kt * 128;
    bf16_t* kl = &sK[bufi][wave * 2048];
    bf16_t* vl = &sVt[bufi][wave * 2048];
#pragma unroll
    for (int i = 0; i < 4; ++i) {
      gld16(kb + koff[i], kl + i * 512);
      gld16(vb + voff[i], vl + i * 512);
    }
  };

  if (ktiles > 0) issueTile(0, 0);
  int bufi = 0;
  for (int kt = 0; kt < ktiles; ++kt) {
    if (kt + 1 < ktiles) {
      issueTile(kt + 1, bufi ^ 1);
      asm volatile("s_waitcnt vmcnt(8)\n\ts_barrier" ::: "memory");
    } else {
      asm volatile("s_waitcnt vmcnt(0)\n\ts_barrier" ::: "memory");
    }

    const bf16_t* kb_ = sK[bufi];
    const bf16_t* vb_ = sVt[bufi];

    // S = Q K^T (log2 domain)
    f32x4 sc[4];
#pragma unroll
    for (int nt = 0; nt < 4; ++nt) sc[nt] = (f32x4){0.f, 0.f, 0.f, 0.f};
#pragma unroll
    for (int ks = 0; ks < 4; ++ks) {
      bf16x8 a = qf[ks];
#pragma unroll
      for (int nt = 0; nt < 4; ++nt) {
        bf16x8 bb = *(const bf16x8*)&kb_[(nt * 16 + col) * 128 + (((ks * 4 + quad) ^ col) * 8)];
        sc[nt] = mfma16(a, bb, sc[nt]);
      }
    }

    // p = 2^S, mask invalid keys, accumulate l, store P (swizzled A-layout)
    const int key0 = kt * 64;
#pragma unroll
    for (int nt = 0; nt < 4; ++nt) {
      bool valid = (key0 + nt * 16 + col) < L;
#pragma unroll
      for (int r = 0; r < 4; ++r) {
        float p = __builtin_amdgcn_exp2f(sc[nt][r]);
        p = valid ? p : 0.f;
        lsum[r] += p;
        int row = quad * 4 + r;
        int keyc = nt * 16 + col;
        int phys = ((keyc >> 3) ^ (row & 7));
        pw[row * 64 + phys * 8 + (keyc & 7)] = (bf16_t)p;
      }
    }

    // O += P V
#pragma unroll
    for (int ks2 = 0; ks2 < 2; ++ks2) {
      bf16x8 a = *(const bf16x8*)&pw[col * 64 + (((ks2 * 4 + quad) ^ (col & 7)) * 8)];
#pragma unroll
      for (int o = 0; o < 8; ++o) {
        bf16x8 bb = *(const bf16x8*)&vb_[(o * 16 + col) * 64 + (((ks2 * 4 + quad) ^ (col & 7)) * 8)];
        Oacc[o] = mfma16(a, bb, Oacc[o]);
      }
    }
    asm volatile("s_barrier" ::: "memory");
    bufi ^= 1;
  }

  // reduce l across the 16 cols sharing each row
#pragma unroll
  for (int off = 1; off < 16; off <<= 1)
#pragma unroll
    for (int r = 0; r < 4; ++r) lsum[r] += __shfl_xor(lsum[r], off, 64);

  // epilogue: masked-suffix closed form (e^{1e-8}==1.0f) + divide + direct store
  const float wmask = (float)(NK - L);
  float invl[4];
#pragma unroll
  for (int r = 0; r < 4; ++r) invl[r] = 1.0f / (lsum[r] + wmask);
  const float* sfv = sufV + b * DVV;
  float* Ob = Out + ((size_t)b * NQ + qt * 64 + wave * 16) * DVV;
#pragma unroll
  for (int o = 0; o < 8; ++o) {
    float svv = sfv[o * 16 + col];
#pragma unroll
    for (int r = 0; r < 4; ++r)
      Ob[(size_t)(quad * 4 + r) * DVV + o * 16 + col] = (Oacc[o][r] + svv) * invl[r];
  }
}

// ================= fallback path (round-1 kernel) if ws too small =================
#define KSTR 152
#define VSTR 88
#define PSTR 72

__global__ void suffix_fb(const float* __restrict__ V, const int* __restrict__ VL,
                          float* __restrict__ ws) {
  int b = blockIdx.x;
  int kc = blockIdx.y;
  int L = load_valid_len(VL, b);
  int k0 = kc * 128, k1 = k0 + 128;
  int lo = max(L, k0);
  int t = threadIdx.x;
  int dv = t & 127;
  int h = t >> 7;
  float s = 0.f;
  for (int k = lo + h; k < k1; k += 2)
    s += V[((size_t)b * NK + k) * DVV + dv];
  __shared__ float part[128];
  if (h == 0) part[dv] = s;
  __syncthreads();
  if (h == 1) atomicAdd(&ws[b * DVV + dv], part[dv] + s);
}

__launch_bounds__(256, 2)
__global__ void attn_fb(const float* __restrict__ Q, const float* __restrict__ K,
                        const float* __restrict__ V, const int* __restrict__ VL,
                        const float* __restrict__ sufV, float* __restrict__ Out) {
  const int flat = blockIdx.x;
  const int b  = flat & 15;
  const int qt = flat >> 4;
  const int L  = load_valid_len(VL, b);

  __shared__ bf16_t sK2[64 * KSTR];
  __shared__ bf16_t sVT2[128 * VSTR];
  __shared__ bf16_t sP2[4 * 16 * PSTR];

  const int tid  = threadIdx.x;
  const int wave = tid >> 6;
  const int lane = tid & 63;
  const int col  = lane & 15;
  const int quad = lane >> 4;

  const float* Qb = Q + ((size_t)b * NQ + qt * 64 + wave * 16) * DD;
  const float* Kb = K + (size_t)b * NK * DD;
  const float* Vb = V + (size_t)b * NK * DVV;

  bf16x8 qf[4];
  {
    const float scq = 0.08838834764831845f;
    const float* qrow = Qb + (size_t)col * DD + quad * 8;
#pragma unroll
    for (int ks = 0; ks < 4; ++ks) {
      float4 u0 = *(const float4*)(qrow + ks * 32);
      float4 u1 = *(const float4*)(qrow + ks * 32 + 4);
      bf16x8 f;
      f[0] = (bf16_t)(u0.x * scq); f[1] = (bf16_t)(u0.y * scq);
      f[2] = (bf16_t)(u0.z * scq); f[3] = (bf16_t)(u0.w * scq);
      f[4] = (bf16_t)(u1.x * scq); f[5] = (bf16_t)(u1.y * scq);
      f[6] = (bf16_t)(u1.z * scq); f[7] = (bf16_t)(u1.w * scq);
      qf[ks] = f;
    }
  }

  f32x4 Oacc[8];
#pragma unroll
  for (int o = 0; o < 8; ++o) Oacc[o] = (f32x4){0.f, 0.f, 0.f, 0.f};
  float m_i[4], l_i[4];
#pragma unroll
  for (int r = 0; r < 4; ++r) { m_i[r] = -1e30f; l_i[r] = 0.f; }

  const int ktiles = (L + 63) >> 6;
  for (int kt = 0; kt < ktiles; ++kt) {
    {
      int r0 = tid >> 5;
      int d4 = (tid & 31) * 4;
      const float* src = Kb + ((size_t)(kt * 64) + r0) * DD + d4;
#pragma unroll
      for (int i = 0; i < 8; ++i) {
        float4 u = *(const float4*)(src + (size_t)i * 8 * DD);
        bf16x4 w4 = {(bf16_t)u.x, (bf16_t)u.y, (bf16_t)u.z, (bf16_t)u.w};
        *(bf16x4*)&sK2[(r0 + i * 8) * KSTR + d4] = w4;
      }
    }
    {
      int r2 = (tid & 31) * 2;
      int dbase = (tid >> 5) * 4;
#pragma unroll
      for (int i = 0; i < 4; ++i) {
        int d4 = dbase + i * 32;
        const float* s0 = Vb + ((size_t)(kt * 64) + r2) * DVV + d4;
        float4 u0 = *(const float4*)s0;
        float4 u1 = *(const float4*)(s0 + DVV);
        *(bf16x2*)&sVT2[(d4 + 0) * VSTR + r2] = (bf16x2){(bf16_t)u0.x, (bf16_t)u1.x};
        *(bf16x2*)&sVT2[(d4 + 1) * VSTR + r2] = (bf16x2){(bf16_t)u0.y, (bf16_t)u1.y};
        *(bf16x2*)&sVT2[(d4 + 2) * VSTR + r2] = (bf16x2){(bf16_t)u0.z, (bf16_t)u1.z};
        *(bf16x2*)&sVT2[(d4 + 3) * VSTR + r2] = (bf16x2){(bf16_t)u0.w, (bf16_t)u1.w};
      }
    }
    __syncthreads();

    f32x4 sv4[4];
#pragma unroll
    for (int nt = 0; nt < 4; ++nt) sv4[nt] = (f32x4){0.f, 0.f, 0.f, 0.f};
#pragma unroll
    for (int ks = 0; ks < 4; ++ks) {
      bf16x8 a = qf[ks];
#pragma unroll
      for (int nt = 0; nt < 4; ++nt) {
        bf16x8 bb = *(const bf16x8*)&sK2[(nt * 16 + col) * KSTR + ks * 32 + quad * 8];
        sv4[nt] = mfma16(a, bb, sv4[nt]);
      }
    }

    const int key0 = kt * 64;
    float sv[4][4];
    float mloc[4] = {-1e30f, -1e30f, -1e30f, -1e30f};
#pragma unroll
    for (int nt = 0; nt < 4; ++nt) {
      int key = key0 + nt * 16 + col;
      bool valid = key < L;
#pragma unroll
      for (int r = 0; r < 4; ++r) {
        float v = valid ? sv4[nt][r] : -1e30f;
        sv[nt][r] = v;
        mloc[r] = fmaxf(mloc[r], v);
      }
    }
#pragma unroll
    for (int off = 1; off < 16; off <<= 1)
#pragma unroll
      for (int r = 0; r < 4; ++r) mloc[r] = fmaxf(mloc[r], __shfl_xor(mloc[r], off, 64));
    float al[4];
#pragma unroll
    for (int r = 0; r < 4; ++r) {
      float mn = fmaxf(m_i[r], mloc[r]);
      al[r] = __expf(m_i[r] - mn);
      m_i[r] = mn;
    }
    float lloc[4] = {0.f, 0.f, 0.f, 0.f};
#pragma unroll
    for (int nt = 0; nt < 4; ++nt)
#pragma unroll
      for (int r = 0; r < 4; ++r) {
        float p = __expf(sv[nt][r] - m_i[r]);
        sv[nt][r] = p;
        lloc[r] += p;
      }
#pragma unroll
    for (int off = 1; off < 16; off <<= 1)
#pragma unroll
      for (int r = 0; r < 4; ++r) lloc[r] += __shfl_xor(lloc[r], off, 64);
#pragma unroll
    for (int r = 0; r < 4; ++r) l_i[r] = l_i[r] * al[r] + lloc[r];
#pragma unroll
    for (int o = 0; o < 8; ++o)
#pragma unroll
      for (int r = 0; r < 4; ++r) Oacc[o][r] *= al[r];

    bf16_t* pw = &sP2[wave * 16 * PSTR];
#pragma unroll
    for (int nt = 0; nt < 4; ++nt)
#pragma unroll
      for (int r = 0; r < 4; ++r)
        pw[(quad * 4 + r) * PSTR + nt * 16 + col] = (bf16_t)sv[nt][r];

#pragma unroll
    for (int ks2 = 0; ks2 < 2; ++ks2) {
      bf16x8 a = *(const bf16x8*)&pw[(lane & 15) * PSTR + ks2 * 32 + quad * 8];
#pragma unroll
      for (int o = 0; o < 8; ++o) {
        bf16x8 bb = *(const bf16x8*)&sVT2[(o * 16 + col) * VSTR + ks2 * 32 + quad * 8];
        Oacc[o] = mfma16(a, bb, Oacc[o]);
      }
    }
    __syncthreads();
  }

  if (L < NK) {
    const float c = 1e-8f;
    const float w = (float)(NK - L);
    float a2[4], ec[4];
#pragma unroll
    for (int r = 0; r < 4; ++r) {
      float mn = fmaxf(m_i[r], c);
      a2[r] = __expf(m_i[r] - mn);
      ec[r] = __expf(c - mn);
      l_i[r] = l_i[r] * a2[r] + w * ec[r];
    }
    const float* sfv = sufV + b * DVV;
#pragma unroll
    for (int o = 0; o < 8; ++o) {
      float svv = sfv[o * 16 + col];
#pragma unroll
      for (int r = 0; r < 4; ++r) Oacc[o][r] = Oacc[o][r] * a2[r] + ec[r] * svv;
    }
  }

  float invl[4];
#pragma unroll
  for (int r = 0; r < 4; ++r) invl[r] = 1.0f / l_i[r];

  float* Ob = Out + ((size_t)b * NQ + qt * 64 + wave * 16) * DVV;
#pragma unroll
  for (int o = 0; o < 8; ++o)
#pragma unroll
    for (int r = 0; r < 4; ++r)
      Ob[(size_t)(quad * 4 + r) * DVV + o * 16 + col] = Oacc[o][r] * invl[r];
}

extern "C" void kernel_launch(void* const* d_in, const int* in_sizes, int n_in,
                              void* d_out, int out_size, void* d_ws, size_t ws_size,
                              hipStream_t stream) {
  const float* Q  = (const float*)d_in[0];
  const float* K  = (const float*)d_in[1];
  const float* V  = (const float*)d_in[2];
  const int*   VL = (const int*)d_in[3];
  float* out = (float*)d_out;

  if (ws_size >= WS_NEED) {
    char* ws = (char*)d_ws;
    bf16_t* Qb = (bf16_t*)(ws + QB_OFF);
    bf16_t* Kb = (bf16_t*)(ws + KB_OFF);
    bf16_t* Vt = (bf16_t*)(ws + VT_OFF);
    float* sufV = (float*)(ws + SUF_OFF);
    int* sched = (int*)(ws + SCH_OFF);

    hipMemsetAsync(sufV, 0, BATCH * DVV * sizeof(float), stream);
    prep_kernel<<<1537, 256, 0, stream>>>(Q, K, V, VL, Qb, Kb, Vt, sufV, sched);
    attn_kernel<<<512, 256, 0, stream>>>(Qb, Kb, Vt, VL, sufV, sched, out);
  } else {
    float* ws = (float*)d_ws;
    hipMemsetAsync(ws, 0, BATCH * DVV * sizeof(float), stream);
    dim3 g1(BATCH, 16);
    suffix_fb<<<g1, 256, 0, stream>>>(V, VL, ws);
    attn_fb<<<BATCH * (NQ / 64), 256, 0, stream>>>(Q, K, V, VL, ws, out);
  }
}